// Round 5
// baseline (228.952 us; speedup 1.0000x reference)
//
#include <hip/hip_runtime.h>
#include <math.h>

// Problem: B=16384, D=512, R=64, E=8.
// out = x0 * (sum_e g_e * (x @ V[e]^T C[e] U[e]^T)) + g@b + x*sum(g)
// Folded: VC[d, e*R+s] = sum_r V[e,r,d] C[e,r,s]  ->  xvc = x @ VC   (GEMM1)
//         t = g-scaled xvc (expert = col/64)      ->  gproj = t @ Ustack (GEMM2)
// R5: LDS-FREE K-loop. Both A and B fragments are direct 16B/lane global loads
//     (Bt layout [n][K-contig] makes the B-frag a mirror of the A-frag). Zero
//     barriers, zero K-loop LDS -> 4 blocks/CU, 16 waves/CU, free per-wave
//     pipelining. B re-reads served by per-XCD L2 (512 KB weights fit easily).
//     R1/R2/R4 all hit an identical ~42 us latency wall at <=8 waves/CU with
//     every pipe <25% busy; this attacks the latency, not throughput.

typedef __bf16 bf16_t;
typedef __attribute__((ext_vector_type(8))) __bf16 bf16x8;
typedef __attribute__((ext_vector_type(4))) __bf16 bf16x4;
typedef __attribute__((ext_vector_type(4))) float  floatx4;

// ---------------- K0: weight prep ------------------------------------------
__global__ __launch_bounds__(256) void prep_kernel(
    const float* __restrict__ U, const float* __restrict__ V, const float* __restrict__ C,
    bf16_t* __restrict__ VCc, bf16_t* __restrict__ Ut) {
  int tid = blockIdx.x * 256 + threadIdx.x;
  if (tid < 512 * 512) {
    int n = tid >> 9, d = tid & 511;
    int e = n >> 6, s = n & 63;
    const float* Vp = V + (size_t)e * 64 * 512 + d;   // V[e,r,d], stride 512 over r
    const float* Cp = C + (size_t)e * 64 * 64 + s;    // C[e,r,s], stride 64 over r
    float acc = 0.f;
#pragma unroll 8
    for (int r = 0; r < 64; ++r) acc += Vp[(size_t)r * 512] * Cp[r * 64];
    VCc[tid] = (bf16_t)acc;
  } else {
    int i2 = tid - 512 * 512;
    int d = i2 >> 9, n = i2 & 511;
    int e = n >> 6, s = n & 63;
    Ut[i2] = (bf16_t)U[((size_t)e * 512 + d) * 64 + s];
  }
}

// ---------------- K1: x -> bf16 cast + gate softmax (one wave per row) -----
__global__ __launch_bounds__(256) void gate_kernel(
    const float* __restrict__ x, const float* __restrict__ Wg, const float* __restrict__ bg,
    bf16_t* __restrict__ xbf, float* __restrict__ g) {
  int wave = threadIdx.x >> 6, lane = threadIdx.x & 63;
  int row = blockIdx.x * 4 + wave;
  const float4* xr = (const float4*)(x + (size_t)row * 512);
  float4 v0 = xr[lane];
  float4 v1 = xr[lane + 64];
  bf16x4* xb = (bf16x4*)(xbf + (size_t)row * 512);
  bf16x4 b0, b1;
  b0.x = (bf16_t)v0.x; b0.y = (bf16_t)v0.y; b0.z = (bf16_t)v0.z; b0.w = (bf16_t)v0.w;
  b1.x = (bf16_t)v1.x; b1.y = (bf16_t)v1.y; b1.z = (bf16_t)v1.z; b1.w = (bf16_t)v1.w;
  xb[lane] = b0;
  xb[lane + 64] = b1;
  float acc[8];
#pragma unroll
  for (int e = 0; e < 8; ++e) {
    const float4* wp = (const float4*)(Wg + (size_t)e * 512);
    float4 w0 = wp[lane], w1 = wp[lane + 64];
    acc[e] = v0.x * w0.x + v0.y * w0.y + v0.z * w0.z + v0.w * w0.w +
             v1.x * w1.x + v1.y * w1.y + v1.z * w1.z + v1.w * w1.w;
  }
#pragma unroll
  for (int e = 0; e < 8; ++e) {
#pragma unroll
    for (int off = 32; off > 0; off >>= 1) acc[e] += __shfl_xor(acc[e], off, 64);
  }
  float z[8], mx = -1e30f;
#pragma unroll
  for (int e = 0; e < 8; ++e) { z[e] = acc[e] + bg[e]; mx = fmaxf(mx, z[e]); }
  float s = 0.f;
#pragma unroll
  for (int e = 0; e < 8; ++e) { z[e] = __expf(z[e] - mx); s += z[e]; }
  float inv = 1.f / s;
  if (lane == 0) {
#pragma unroll
    for (int e = 0; e < 8; ++e) g[(size_t)row * 8 + e] = z[e] * inv;
  }
}

// ---------------- LDS-free streaming GEMM core -----------------------------
// A [M][512] bf16 row-major; Bt [N][512] bf16 (col n's K contiguous).
// Block 128m x 64n, 4 waves; wave = 32 rows (2 m-frags) x 64 cols (4 n-frags).
// A-frag lane(llo,lhi): A[m0+w*32+(mf*16)+llo][ks*32 + lhi*8 ..+8)  (16B)
// B-frag lane(llo,lhi): Bt[n0+nf*16+llo][ks*32 + lhi*8 ..+8)        (16B)
__device__ __forceinline__ void gemm_stream(
    const bf16_t* __restrict__ A, const bf16_t* __restrict__ Bt,
    int m0, int n0, int t, floatx4 acc[2][4]) {
  const int lane = t & 63, wave = t >> 6;
  const int lhi = lane >> 4, llo = lane & 15;
  const char* pA0 = (const char*)A + (size_t)(m0 + wave * 32 + llo) * 1024 + lhi * 16;
  const char* pA1 = pA0 + 16 * 1024;
  const char* pB  = (const char*)Bt + (size_t)(n0 + llo) * 1024 + lhi * 16;
#pragma unroll 4
  for (int ks = 0; ks < 16; ++ks) {
    bf16x8 a0 = *(const bf16x8*)(pA0 + ks * 64);
    bf16x8 a1 = *(const bf16x8*)(pA1 + ks * 64);
    bf16x8 bf[4];
#pragma unroll
    for (int nf = 0; nf < 4; ++nf)
      bf[nf] = *(const bf16x8*)(pB + (size_t)nf * 16 * 1024 + ks * 64);
#pragma unroll
    for (int nf = 0; nf < 4; ++nf) {
      acc[0][nf] = __builtin_amdgcn_mfma_f32_16x16x32_bf16(a0, bf[nf], acc[0][nf], 0, 0, 0);
      acc[1][nf] = __builtin_amdgcn_mfma_f32_16x16x32_bf16(a1, bf[nf], acc[1][nf], 0, 0, 0);
    }
  }
}

// ---------------- K2: GEMM1 + gate-scale epilogue -> T (bf16) --------------
__global__ __launch_bounds__(256, 4) void gemm1_kernel(
    const bf16_t* __restrict__ xbf, const bf16_t* __restrict__ VCc,
    const float* __restrict__ g, bf16_t* __restrict__ T) {
  __shared__ float gcol[128];
  const int t = threadIdx.x;
  const int m0 = blockIdx.x * 128, n0 = blockIdx.y * 64;
  floatx4 acc[2][4];
#pragma unroll
  for (int i = 0; i < 2; ++i)
#pragma unroll
    for (int j = 0; j < 4; ++j) acc[i][j] = (floatx4){0.f, 0.f, 0.f, 0.f};
  if (t < 128) gcol[t] = g[(size_t)(m0 + t) * 8 + (n0 >> 6)];
  gemm_stream(xbf, VCc, m0, n0, t, acc);
  __syncthreads();  // gcol visible (the kernel's only barrier)
  const int lane = t & 63, wave = t >> 6;
  const int lhi = lane >> 4, llo = lane & 15;
#pragma unroll
  for (int mf = 0; mf < 2; ++mf) {
#pragma unroll
    for (int r = 0; r < 4; ++r) {
      int rml = wave * 32 + mf * 16 + lhi * 4 + r;  // C/D: col=lane&15, row=quad*4+reg
      float gv = gcol[rml];
      size_t mrow = (size_t)(m0 + rml) * 512;
#pragma unroll
      for (int nf = 0; nf < 4; ++nf)
        T[mrow + n0 + nf * 16 + llo] = (bf16_t)(acc[mf][nf][r] * gv);
    }
  }
}

// ---------------- K3: GEMM2 + final epilogue -> out (f32) ------------------
__global__ __launch_bounds__(256, 4) void gemm2_kernel(
    const bf16_t* __restrict__ T, const bf16_t* __restrict__ Ut,
    const float* __restrict__ g, const float* __restrict__ bvec,
    const float* __restrict__ x0, const float* __restrict__ x,
    float* __restrict__ out) {
  __shared__ float ldsG[1024];   // g-slab [128][8]
  __shared__ float ldsBv[512];   // b-slab [8][64]
  const int t = threadIdx.x;
  const int m0 = blockIdx.x * 128, n0 = blockIdx.y * 64;
  floatx4 acc[2][4];
#pragma unroll
  for (int i = 0; i < 2; ++i)
#pragma unroll
    for (int j = 0; j < 4; ++j) acc[i][j] = (floatx4){0.f, 0.f, 0.f, 0.f};
  ((float4*)ldsG)[t] = ((const float4*)(g + (size_t)m0 * 8))[t];
  if (t < 128)
    ((float4*)ldsBv)[t] = ((const float4*)bvec)[(t >> 4) * 128 + (n0 >> 2) + (t & 15)];
  gemm_stream(T, Ut, m0, n0, t, acc);
  __syncthreads();  // slabs visible (the kernel's only barrier)
  const int lane = t & 63, wave = t >> 6;
  const int lhi = lane >> 4, llo = lane & 15;
  float bb[4][8];
#pragma unroll
  for (int nf = 0; nf < 4; ++nf) {
    int nl = nf * 16 + llo;
#pragma unroll
    for (int e = 0; e < 8; ++e) bb[nf][e] = ldsBv[e * 64 + nl];
  }
#pragma unroll
  for (int mf = 0; mf < 2; ++mf) {
#pragma unroll
    for (int r = 0; r < 4; ++r) {
      int rml = wave * 32 + mf * 16 + lhi * 4 + r;
      float4 ga = ((const float4*)ldsG)[rml * 2];
      float4 gb2 = ((const float4*)ldsG)[rml * 2 + 1];
      float g8[8] = {ga.x, ga.y, ga.z, ga.w, gb2.x, gb2.y, gb2.z, gb2.w};
      float gsum = g8[0] + g8[1] + g8[2] + g8[3] + g8[4] + g8[5] + g8[6] + g8[7];
      size_t mrow = (size_t)(m0 + rml) * 512;
#pragma unroll
      for (int nf = 0; nf < 4; ++nf) {
        int n = n0 + nf * 16 + llo;
        float bias = 0.f;
#pragma unroll
        for (int e = 0; e < 8; ++e) bias += g8[e] * bb[nf][e];
        size_t idx = mrow + n;
        out[idx] = x0[idx] * acc[mf][nf][r] + bias + x[idx] * gsum;
      }
    }
  }
}

// ---------------- launch ----------------------------------------------------
extern "C" void kernel_launch(void* const* d_in, const int* in_sizes, int n_in,
                              void* d_out, int out_size, void* d_ws, size_t ws_size,
                              hipStream_t stream) {
  const float* x0 = (const float*)d_in[0];
  const float* x  = (const float*)d_in[1];
  const float* U  = (const float*)d_in[2];
  const float* V  = (const float*)d_in[3];
  const float* C  = (const float*)d_in[4];
  const float* bv = (const float*)d_in[5];
  const float* Wg = (const float*)d_in[6];
  const float* bg = (const float*)d_in[7];
  float* out = (float*)d_out;

  char* ws = (char*)d_ws;
  bf16_t* xbf = (bf16_t*)(ws);                               // 16,777,216 B
  bf16_t* T   = (bf16_t*)(ws + 16777216);                    // 16,777,216 B
  bf16_t* VCc = (bf16_t*)(ws + 33554432);                    //    524,288 B
  bf16_t* Ut  = (bf16_t*)(ws + 34078720);                    //    524,288 B
  float*  g   = (float*)(ws + 34603008);                     //    524,288 B

  prep_kernel<<<2048, 256, 0, stream>>>(U, V, C, VCc, Ut);
  gate_kernel<<<4096, 256, 0, stream>>>(x, Wg, bg, xbf, g);
  gemm1_kernel<<<dim3(128, 8), 256, 0, stream>>>(xbf, VCc, g, T);
  gemm2_kernel<<<dim3(128, 8), 256, 0, stream>>>(T, Ut, g, bv, x0, x, out);
}

// Round 6
// 188.905 us; speedup vs baseline: 1.2120x; 1.2120x over previous
//
#include <hip/hip_runtime.h>
#include <math.h>

// Problem: B=16384, D=512, R=64, E=8.
// out = x0 * (sum_e g_e * (x @ V[e]^T C[e] U[e]^T)) + g@b + x      (g.sum==1!)
// Folded: VC[d, e*R+s] = sum_r V[e,r,d] C[e,r,s]  ->  xvc = x @ VC   (GEMM1)
//         T = g-scaled xvc (expert = col/64)      ->  gproj = T @ Ustack (GEMM2)
// R6: FULLY FUSED. Evidence from R1-R5: every multi-kernel structure pins at
//     ~2 TB/s achieved HBM -> cut traffic instead. One kernel, 32-row slabs:
//     x read once -> bf16 LDS; gate via 1-wave MFMA (zero-padded Wgt);
//     GEMM1 -> T in LDS (never HBM); GEMM2; epilogue reads only x0.
//     HBM: ~97 MB vs ~190 MB before. 512 blk x 512 thr, 66 KB LDS, 2 blk/CU.

typedef __bf16 bf16_t;
typedef __attribute__((ext_vector_type(8))) __bf16 bf16x8;
typedef __attribute__((ext_vector_type(4))) float  floatx4;

// ---------------- K0: weight prep ------------------------------------------
// VCc[n][d] (n=e*64+s): Bt layout for GEMM1 B-operand, bf16 [512][512]
// Ut [d][j] (j=e*64+s): Bt layout for GEMM2 B-operand, bf16 [512][512]
// Wgt[16][512]: gate B-operand, rows 8..15 zero (pad to MFMA n=16)
__global__ __launch_bounds__(256) void prep_kernel(
    const float* __restrict__ U, const float* __restrict__ V, const float* __restrict__ C,
    const float* __restrict__ Wg,
    bf16_t* __restrict__ VCc, bf16_t* __restrict__ Ut, bf16_t* __restrict__ Wgt) {
  int tid = blockIdx.x * 256 + threadIdx.x;
  if (tid < 512 * 512) {
    int n = tid >> 9, d = tid & 511;
    int e = n >> 6, s = n & 63;
    const float* Vp = V + (size_t)e * 64 * 512 + d;   // V[e,r,d], stride 512 over r
    const float* Cp = C + (size_t)e * 64 * 64 + s;    // C[e,r,s], stride 64 over r
    float acc = 0.f;
#pragma unroll 8
    for (int r = 0; r < 64; ++r) acc += Vp[(size_t)r * 512] * Cp[r * 64];
    VCc[tid] = (bf16_t)acc;
  } else if (tid < 2 * 512 * 512) {
    int i2 = tid - 512 * 512;
    int d = i2 >> 9, n = i2 & 511;
    int e = n >> 6, s = n & 63;
    Ut[i2] = (bf16_t)U[((size_t)e * 512 + d) * 64 + s];
  } else {
    int i3 = tid - 2 * 512 * 512;            // 16*512 entries
    int n = i3 >> 9;
    Wgt[i3] = (n < 8) ? (bf16_t)Wg[i3] : (bf16_t)0.f;
  }
}

// 16B-chunk XOR swizzle within each 1KB row: chunk c of row r -> slot below.
__device__ __forceinline__ int swz(int c, int r) { return (c & ~7) | ((c ^ r) & 7); }

__device__ __forceinline__ bf16x8 frag_lds(const char* base, int row, int c) {
  return *(const bf16x8*)(base + row * 1024 + swz(c, row) * 16);
}

// ---------------- K1: fully fused ------------------------------------------
__global__ __launch_bounds__(512, 4) void fused_kernel(
    const float* __restrict__ x0, const float* __restrict__ x,
    const bf16_t* __restrict__ VCc, const bf16_t* __restrict__ Ut,
    const bf16_t* __restrict__ Wgt, const float* __restrict__ bg,
    const float* __restrict__ bvec, float* __restrict__ out) {
  __shared__ char ldsX[32768];     // xbf slab [32 rows][64 chunks x 16B] swizzled
  __shared__ char ldsT[32768];     // T slab, same layout
  __shared__ float ldsG[32 * 8];   // g[row][e]

  const int t = threadIdx.x;
  const int wave = t >> 6, lane = t & 63;
  const int lhi = lane >> 4, llo = lane & 15;
  const int m0 = blockIdx.x * 32;

  // ---- P0: x (f32, HBM, read once) -> bf16 LDS slab --------------------------
#pragma unroll
  for (int i = 0; i < 4; ++i) {
    int C = i * 512 + t;               // chunk id 0..2047
    int r = C >> 6, c = C & 63;
    const float* src = x + (size_t)(m0 + r) * 512 + c * 8;
    float4 f0 = *(const float4*)src;
    float4 f1 = *(const float4*)(src + 4);
    bf16x8 v;
    v[0] = (bf16_t)f0.x; v[1] = (bf16_t)f0.y; v[2] = (bf16_t)f0.z; v[3] = (bf16_t)f0.w;
    v[4] = (bf16_t)f1.x; v[5] = (bf16_t)f1.y; v[6] = (bf16_t)f1.z; v[7] = (bf16_t)f1.w;
    *(bf16x8*)(ldsX + r * 1024 + swz(c, r) * 16) = v;
  }
  __syncthreads();

  // ---- gate (wave 0 only): logits = xbf @ Wgt^T via MFMA, then softmax -------
  if (wave == 0) {
    floatx4 ga[2];
    ga[0] = (floatx4){0.f, 0.f, 0.f, 0.f};
    ga[1] = (floatx4){0.f, 0.f, 0.f, 0.f};
#pragma unroll 4
    for (int ks = 0; ks < 16; ++ks) {
      bf16x8 bW = *(const bf16x8*)((const char*)Wgt + (size_t)llo * 1024 + ks * 64 + lhi * 16);
      ga[0] = __builtin_amdgcn_mfma_f32_16x16x32_bf16(frag_lds(ldsX, llo, ks * 4 + lhi), bW, ga[0], 0, 0, 0);
      ga[1] = __builtin_amdgcn_mfma_f32_16x16x32_bf16(frag_lds(ldsX, 16 + llo, ks * 4 + lhi), bW, ga[1], 0, 0, 0);
    }
    float bgv = bg[llo & 7];
#pragma unroll
    for (int mf = 0; mf < 2; ++mf) {
#pragma unroll
      for (int r = 0; r < 4; ++r) {
        float z = ga[mf][r] + bgv;     // cols 8..15 are garbage but stay in their own xor-group
        float mx = z;
        mx = fmaxf(mx, __shfl_xor(mx, 1, 64));
        mx = fmaxf(mx, __shfl_xor(mx, 2, 64));
        mx = fmaxf(mx, __shfl_xor(mx, 4, 64));
        float ez = __expf(z - mx);
        float s8 = ez;
        s8 += __shfl_xor(s8, 1, 64);
        s8 += __shfl_xor(s8, 2, 64);
        s8 += __shfl_xor(s8, 4, 64);
        if (llo < 8) ldsG[(mf * 16 + lhi * 4 + r) * 8 + llo] = ez / s8;
      }
    }
  }

  // ---- GEMM1: xvc = xbf @ VCc (A from LDS, B from L2-hot global) -------------
  floatx4 acc[2][4];
#pragma unroll
  for (int i = 0; i < 2; ++i)
#pragma unroll
    for (int j = 0; j < 4; ++j) acc[i][j] = (floatx4){0.f, 0.f, 0.f, 0.f};
  {
    const char* pB = (const char*)VCc + (size_t)(wave * 64 + llo) * 1024 + lhi * 16;
#pragma unroll 2
    for (int ks = 0; ks < 16; ++ks) {
      bf16x8 a0 = frag_lds(ldsX, llo, ks * 4 + lhi);
      bf16x8 a1 = frag_lds(ldsX, 16 + llo, ks * 4 + lhi);
      bf16x8 bf[4];
#pragma unroll
      for (int nf = 0; nf < 4; ++nf)
        bf[nf] = *(const bf16x8*)(pB + (size_t)nf * 16 * 1024 + ks * 64);
#pragma unroll
      for (int nf = 0; nf < 4; ++nf) {
        acc[0][nf] = __builtin_amdgcn_mfma_f32_16x16x32_bf16(a0, bf[nf], acc[0][nf], 0, 0, 0);
        acc[1][nf] = __builtin_amdgcn_mfma_f32_16x16x32_bf16(a1, bf[nf], acc[1][nf], 0, 0, 0);
      }
    }
  }
  __syncthreads();   // g written (wave0 pre-GEMM), all waves done with gate needs

  // ---- scale by g (expert = wave) and write T to LDS -------------------------
#pragma unroll
  for (int mf = 0; mf < 2; ++mf) {
#pragma unroll
    for (int r = 0; r < 4; ++r) {
      int m = mf * 16 + lhi * 4 + r;         // C/D: col=lane&15, row=quad*4+reg
      float gv = ldsG[m * 8 + wave];
#pragma unroll
      for (int nf = 0; nf < 4; ++nf) {
        int n = wave * 64 + nf * 16 + llo;
        int c = n >> 3;
        *(bf16_t*)(ldsT + m * 1024 + swz(c, m) * 16 + (n & 7) * 2) =
            (bf16_t)(acc[mf][nf][r] * gv);
      }
    }
  }
  __syncthreads();

  // ---- GEMM2: gproj = T @ Ut -------------------------------------------------
#pragma unroll
  for (int i = 0; i < 2; ++i)
#pragma unroll
    for (int j = 0; j < 4; ++j) acc[i][j] = (floatx4){0.f, 0.f, 0.f, 0.f};
  {
    const char* pB = (const char*)Ut + (size_t)(wave * 64 + llo) * 1024 + lhi * 16;
#pragma unroll 2
    for (int ks = 0; ks < 16; ++ks) {
      bf16x8 a0 = frag_lds(ldsT, llo, ks * 4 + lhi);
      bf16x8 a1 = frag_lds(ldsT, 16 + llo, ks * 4 + lhi);
      bf16x8 bf[4];
#pragma unroll
      for (int nf = 0; nf < 4; ++nf)
        bf[nf] = *(const bf16x8*)(pB + (size_t)nf * 16 * 1024 + ks * 64);
#pragma unroll
      for (int nf = 0; nf < 4; ++nf) {
        acc[0][nf] = __builtin_amdgcn_mfma_f32_16x16x32_bf16(a0, bf[nf], acc[0][nf], 0, 0, 0);
        acc[1][nf] = __builtin_amdgcn_mfma_f32_16x16x32_bf16(a1, bf[nf], acc[1][nf], 0, 0, 0);
      }
    }
  }
  // no barrier needed: epilogue reads ldsX/ldsG (stable) + own acc

  // ---- epilogue: out = x0*gproj + g@b + x  (x from LDS bf16; g.sum==1) ------
  float bvn[4][8];
#pragma unroll
  for (int nf = 0; nf < 4; ++nf) {
    int n = wave * 64 + nf * 16 + llo;
#pragma unroll
    for (int e = 0; e < 8; ++e) bvn[nf][e] = bvec[(size_t)e * 512 + n];
  }
#pragma unroll
  for (int mf = 0; mf < 2; ++mf) {
#pragma unroll
    for (int r = 0; r < 4; ++r) {
      int m = mf * 16 + lhi * 4 + r;
      float4 glo = *(const float4*)&ldsG[m * 8];
      float4 ghi = *(const float4*)&ldsG[m * 8 + 4];
      float g8[8] = {glo.x, glo.y, glo.z, glo.w, ghi.x, ghi.y, ghi.z, ghi.w};
      size_t row = (size_t)(m0 + m) * 512;
#pragma unroll
      for (int nf = 0; nf < 4; ++nf) {
        int n = wave * 64 + nf * 16 + llo;
        float bias = 0.f;
#pragma unroll
        for (int e = 0; e < 8; ++e) bias += g8[e] * bvn[nf][e];
        int c = n >> 3;
        float xb = (float)*(const bf16_t*)(ldsX + m * 1024 + swz(c, m) * 16 + (n & 7) * 2);
        out[row + n] = x0[row + n] * acc[mf][nf][r] + bias + xb;
      }
    }
  }
}

// ---------------- launch ----------------------------------------------------
extern "C" void kernel_launch(void* const* d_in, const int* in_sizes, int n_in,
                              void* d_out, int out_size, void* d_ws, size_t ws_size,
                              hipStream_t stream) {
  const float* x0 = (const float*)d_in[0];
  const float* x  = (const float*)d_in[1];
  const float* U  = (const float*)d_in[2];
  const float* V  = (const float*)d_in[3];
  const float* C  = (const float*)d_in[4];
  const float* bv = (const float*)d_in[5];
  const float* Wg = (const float*)d_in[6];
  const float* bg = (const float*)d_in[7];
  float* out = (float*)d_out;

  char* ws = (char*)d_ws;
  bf16_t* VCc = (bf16_t*)(ws);                 // 524,288 B
  bf16_t* Ut  = (bf16_t*)(ws + 524288);        // 524,288 B
  bf16_t* Wgt = (bf16_t*)(ws + 1048576);       //  16,384 B

  prep_kernel<<<2080, 256, 0, stream>>>(U, V, C, Wg, VCc, Ut, Wgt);
  fused_kernel<<<512, 512, 0, stream>>>(x0, x, VCc, Ut, Wgt, bg, bv, out);
}